// Round 9
// baseline (318.827 us; speedup 1.0000x reference)
//
#include <hip/hip_runtime.h>
#include <math.h>

// B=8, L=2048, D=512, fp32 in/out. bf16 MFMA GEMMs. Column-softmax
// (axis=1 = query axis i): colsum[j]=sum_i exp(S[i,j]); out = exp(S) @ (vp/colsum).
// R1: qp pre-scaled by log2(e); S kernel uses exp2 (v_exp_f32).
// R3: LDS XOR-swizzle (col16B ^= (row>>1)&3); bank conflicts 6.3M -> 0.
// R4/R5 LESSON: prefetch under __syncthreads is neutral-to-worse (vmcnt(0) drain).
// R6/R7 LESSON: f32-direct proj is latency-bound (79us) regardless of issue
//     order -> revert to bf16 prep + gload_lds proj (proven 298us config).
// R8: pv_gemm gets TRUE counted-vmcnt pipelining (T4): raw s_barrier +
//     s_waitcnt vmcnt(6), 2 buffers, depth-2 flight. Loads are never
//     drained to 0 in the main loop - the missing mechanism in R4/R5.

#define TKK 32

typedef __attribute__((ext_vector_type(8))) short bf16x8;
typedef __attribute__((ext_vector_type(4))) float floatx4;

typedef __attribute__((address_space(3))) short lds_short;
typedef const __attribute__((address_space(1))) short glob_short;

__device__ __forceinline__ short f2bf(float x) {
    unsigned u = __float_as_uint(x);
    u += 0x7fff + ((u >> 16) & 1);   // round-to-nearest-even
    return (short)(u >> 16);
}
__device__ __forceinline__ float bf2f(short s) {
    return __uint_as_float(((unsigned)(unsigned short)s) << 16);
}
__device__ __forceinline__ float exp2_fast(float x) {
    float r;
    asm("v_exp_f32 %0, %1" : "=v"(r) : "v"(x));
    return r;
}

// Stage-side swizzled column (shorts): sr = lane>>2, unit = lane&3,
// swz = (lane>>3)&3 (row-within-chunk >>1).
#define STAGE_SC(lane) ((((lane) & 3) ^ (((lane) >> 3) & 3)) * 8)
// Read-side swizzled fragment column (shorts): h = lane>>4, s(row)=(lane>>1)&3.
#define FRAG_FC(lane) (((((lane) >> 4) ^ (((lane) >> 1) & 3))) * 8)

// ---- fused prep: cast q/k/v (3*4096 blocks), cast W's (3*128), zero colsum (64)
__global__ __launch_bounds__(256) void prep(
    const float* __restrict__ q, const float* __restrict__ k,
    const float* __restrict__ v,
    const float* __restrict__ Wq, const float* __restrict__ Wk,
    const float* __restrict__ Wv,
    short* __restrict__ q_bf, short* __restrict__ k_bf, short* __restrict__ v_bf,
    short* __restrict__ Wq_bf, short* __restrict__ Wk_bf, short* __restrict__ Wv_bf,
    float* __restrict__ colsum)
{
    const int b = blockIdx.x;
    const float* in = nullptr;
    short* out = nullptr;
    long long i;
    if (b < 12288) {
        const int z = b >> 12;
        in  = (z == 0) ? q    : (z == 1) ? k    : v;
        out = (z == 0) ? q_bf : (z == 1) ? k_bf : v_bf;
        i = ((long long)(b & 4095) * 256 + threadIdx.x) * 8;
    } else if (b < 12672) {
        const int z = (b - 12288) >> 7;
        in  = (z == 0) ? Wq    : (z == 1) ? Wk    : Wv;
        out = (z == 0) ? Wq_bf : (z == 1) ? Wk_bf : Wv_bf;
        i = ((long long)((b - 12288) & 127) * 256 + threadIdx.x) * 8;
    } else {
        colsum[(b - 12672) * 256 + threadIdx.x] = 0.f;
        return;
    }
    float4 x = *(const float4*)(in + i);
    float4 y = *(const float4*)(in + i + 4);
    bf16x8 r;
    r[0] = f2bf(x.x); r[1] = f2bf(x.y); r[2] = f2bf(x.z); r[3] = f2bf(x.w);
    r[4] = f2bf(y.x); r[5] = f2bf(y.y); r[6] = f2bf(y.z); r[7] = f2bf(y.w);
    *(bf16x8*)(out + i) = r;
}

// ---------------- generic NT MFMA gemm body (R3 structure) ----------------
// C[m,n] = (sum_k A[m,k]*B[n,k] + bias[n]) * escale; A:[M][K], B:[N][K] bf16.
template<int TMp, int TNp, int WM, int WN, int HAS_BIAS, int OUT_BF16>
__device__ __forceinline__ void gemm_body(
    const short* __restrict__ A, const short* __restrict__ B,
    const float* __restrict__ bias, void* __restrict__ C,
    int N, int K, int m0, int n0, float escale)
{
    __shared__ short As[TMp * TKK];
    __shared__ short Bs[TNp * TKK];
    constexpr int MI = TMp / (16 * WM);
    constexpr int NJ = TNp / (16 * WN);
    const int t    = threadIdx.x;
    const int wave = t >> 6;
    const int lane = t & 63;
    const int wm = (wave / WN) * (TMp / WM);
    const int wn = (wave % WN) * (TNp / WN);
    const int sr = lane >> 2;
    const int sc = STAGE_SC(lane);
    const int fc = FRAG_FC(lane);

    floatx4 acc[MI][NJ];
    #pragma unroll
    for (int i = 0; i < MI; ++i)
        #pragma unroll
        for (int j = 0; j < NJ; ++j)
            acc[i][j] = (floatx4){0.f, 0.f, 0.f, 0.f};

    for (int k0 = 0; k0 < K; k0 += TKK) {
        #pragma unroll
        for (int c = wave; c < TMp / 16; c += 4)
            __builtin_amdgcn_global_load_lds(
                (glob_short*)(A + (long long)(m0 + c * 16 + sr) * K + k0 + sc),
                (lds_short*)(As + c * 512), 16, 0, 0);
        #pragma unroll
        for (int c = wave; c < TNp / 16; c += 4)
            __builtin_amdgcn_global_load_lds(
                (glob_short*)(B + (long long)(n0 + c * 16 + sr) * K + k0 + sc),
                (lds_short*)(Bs + c * 512), 16, 0, 0);
        __syncthreads();
        bf16x8 af[MI], bfr[NJ];
        #pragma unroll
        for (int i = 0; i < MI; ++i)
            af[i] = *(const bf16x8*)&As[(wm + i * 16 + (lane & 15)) * TKK + fc];
        #pragma unroll
        for (int j = 0; j < NJ; ++j)
            bfr[j] = *(const bf16x8*)&Bs[(wn + j * 16 + (lane & 15)) * TKK + fc];
        #pragma unroll
        for (int i = 0; i < MI; ++i)
            #pragma unroll
            for (int j = 0; j < NJ; ++j)
                acc[i][j] = __builtin_amdgcn_mfma_f32_16x16x32_bf16(af[i], bfr[j], acc[i][j], 0, 0, 0);
        __syncthreads();
    }

    // Epilogue: C/D layout col=lane&15, row=(lane>>4)*4+reg (m89-verified)
    #pragma unroll
    for (int i = 0; i < MI; ++i) {
        const int rbase = m0 + wm + i * 16 + (lane >> 4) * 4;
        #pragma unroll
        for (int j = 0; j < NJ; ++j) {
            const int col = n0 + wn + j * 16 + (lane & 15);
            const float bb = HAS_BIAS ? bias[col] : 0.f;
            #pragma unroll
            for (int r = 0; r < 4; ++r) {
                const long long off = (long long)(rbase + r) * N + col;
                const float vvv = (acc[i][j][r] + bb) * escale;
                if (OUT_BF16) ((short*)C)[off] = f2bf(vvv);
                else          ((float*)C)[off] = vvv;
            }
        }
    }
}

// ---- fused projections: z in {0,1,2} selects (x, W, bias, out) ----
__global__ __launch_bounds__(256) void proj_gemm(
    const short* __restrict__ x0, const short* __restrict__ x1, const short* __restrict__ x2,
    const short* __restrict__ w0, const short* __restrict__ w1, const short* __restrict__ w2,
    const float* __restrict__ b0, const float* __restrict__ b1, const float* __restrict__ b2,
    short* __restrict__ y0, short* __restrict__ y1, short* __restrict__ y2,
    int N, int K)
{
    const int z = blockIdx.z;
    const short* A    = (z == 0) ? x0 : (z == 1) ? x1 : x2;
    const short* B    = (z == 0) ? w0 : (z == 1) ? w1 : w2;
    const float* bias = (z == 0) ? b0 : (z == 1) ? b1 : b2;
    short*       C    = (z == 0) ? y0 : (z == 1) ? y1 : y2;
    const float esc   = (z == 0) ? 1.4426950408889634f : 1.0f;
    gemm_body<128, 128, 2, 2, 1, 1>(A, B, bias, C, N, K,
                                    blockIdx.x * 128, blockIdx.y * 128, esc);
}

// ---- PV gemm: out = E @ vpT^T ----
// R8: 128x64 tile, counted-vmcnt pipeline: 2 buffers of a full 64-K tile,
// depth-2 load flight, s_waitcnt vmcnt(6) (never 0 in the main loop).
__global__ __launch_bounds__(256) void pv_gemm(
    const short* __restrict__ Eg, const short* __restrict__ vpTg,
    float* __restrict__ outg, int N, int K,
    long long sA, long long sB, long long sC)
{
    __shared__ short As[2][2][128 * TKK];   // [buf][half]
    __shared__ short Bs[2][2][64 * TKK];
    const int bz = blockIdx.z;
    const short* A = Eg   + (long long)bz * sA;
    const short* B = vpTg + (long long)bz * sB;
    float*       C = outg + (long long)bz * sC;

    const int m0 = blockIdx.x * 128;
    const int n0 = blockIdx.y * 64;
    const int t    = threadIdx.x;
    const int wave = t >> 6;
    const int lane = t & 63;
    const int wm = (wave >> 1) * 64;
    const int wn = (wave & 1)  * 32;
    const int sr = lane >> 2;
    const int sc = STAGE_SC(lane);
    const int fc = FRAG_FC(lane);

    // Each thread issues exactly 6 gload_lds per stage (4 A + 2 B) -> vmcnt(6)
    // waits precisely for the previous tile's loads.
    auto stage = [&](int buf, int k0) {
        #pragma unroll
        for (int h = 0; h < 2; ++h) {
            const int kk = k0 + h * TKK;
            #pragma unroll
            for (int c = wave; c < 8; c += 4)
                __builtin_amdgcn_global_load_lds(
                    (glob_short*)(A + (long long)(m0 + c * 16 + sr) * K + kk + sc),
                    (lds_short*)(As[buf][h] + c * 512), 16, 0, 0);
            __builtin_amdgcn_global_load_lds(
                (glob_short*)(B + (long long)(n0 + wave * 16 + sr) * K + kk + sc),
                (lds_short*)(Bs[buf][h] + wave * 512), 16, 0, 0);
        }
    };

    floatx4 acc[4][2];
    #pragma unroll
    for (int i = 0; i < 4; ++i)
        #pragma unroll
        for (int j = 0; j < 2; ++j)
            acc[i][j] = (floatx4){0.f, 0.f, 0.f, 0.f};

    const int NT = K / (2 * TKK);   // 32 tiles of 64-K
    // Prologue: 2 tiles in flight; wait only for tile 0 (vmcnt(6)).
    stage(0, 0);
    stage(1, 2 * TKK);
    asm volatile("s_waitcnt vmcnt(6)" ::: "memory");
    __builtin_amdgcn_sched_barrier(0);
    __builtin_amdgcn_s_barrier();
    __builtin_amdgcn_sched_barrier(0);

    int cur = 0;
    for (int tt = 0; tt < NT; ++tt) {
        // Compute on buf[cur] (reads forced complete by MFMA operand waits).
        #pragma unroll
        for (int h = 0; h < 2; ++h) {
            bf16x8 af[4], bfr[2];
            #pragma unroll
            for (int i = 0; i < 4; ++i)
                af[i] = *(const bf16x8*)&As[cur][h][(wm + i * 16 + (lane & 15)) * TKK + fc];
            #pragma unroll
            for (int j = 0; j < 2; ++j)
                bfr[j] = *(const bf16x8*)&Bs[cur][h][(wn + j * 16 + (lane & 15)) * TKK + fc];
            #pragma unroll
            for (int i = 0; i < 4; ++i)
                #pragma unroll
                for (int j = 0; j < 2; ++j)
                    acc[i][j] = __builtin_amdgcn_mfma_f32_16x16x32_bf16(af[i], bfr[j], acc[i][j], 0, 0, 0);
        }
        __builtin_amdgcn_sched_barrier(0);
        __builtin_amdgcn_s_barrier();          // all waves done reading buf[cur]
        __builtin_amdgcn_sched_barrier(0);
        if (tt + 2 < NT) {
            stage(cur, (tt + 2) * 2 * TKK);    // restage consumed buffer
            __builtin_amdgcn_sched_barrier(0);
            asm volatile("s_waitcnt vmcnt(6)" ::: "memory");  // tile tt+1 landed
        } else {
            asm volatile("s_waitcnt vmcnt(0)" ::: "memory");  // tail drain
        }
        __builtin_amdgcn_sched_barrier(0);
        __builtin_amdgcn_s_barrier();          // buf[cur^1] visible to all
        __builtin_amdgcn_sched_barrier(0);
        cur ^= 1;
    }

    #pragma unroll
    for (int i = 0; i < 4; ++i) {
        const int rbase = m0 + wm + i * 16 + (lane >> 4) * 4;
        #pragma unroll
        for (int j = 0; j < 2; ++j) {
            const int col = n0 + wn + j * 16 + (lane & 15);
            #pragma unroll
            for (int r = 0; r < 4; ++r)
                C[(long long)(rbase + r) * N + col] = acc[i][j][r];
        }
    }
}

// ---- NT MFMA gemm with fused exp2 + column-sum (exact R3 structure) ----
__global__ __launch_bounds__(256) void gemm_nt_exp_colsum(
    const short* __restrict__ A, const short* __restrict__ B,
    short* __restrict__ E, float* __restrict__ colsum,
    int N, int K, long long sA, long long sB, long long sE)
{
    __shared__ short As[2][128 * TKK];
    __shared__ short Bs[2][128 * TKK];
    __shared__ float wsum[4][64];
    const int bz = blockIdx.z;
    A += (long long)bz * sA;
    B += (long long)bz * sB;
    E += (long long)bz * sE;
    colsum += (long long)bz * N;

    const int m0 = blockIdx.x * 128;
    const int n0 = blockIdx.y * 128;
    const int t    = threadIdx.x;
    const int wave = t >> 6;
    const int lane = t & 63;
    const int wm = (wave >> 1) * 64;
    const int wn = (wave & 1)  * 64;
    const int sr = lane >> 2;
    const int sc = STAGE_SC(lane);
    const int fc = FRAG_FC(lane);

    floatx4 acc[4][4];
    #pragma unroll
    for (int i = 0; i < 4; ++i)
        #pragma unroll
        for (int j = 0; j < 4; ++j)
            acc[i][j] = (floatx4){0.f, 0.f, 0.f, 0.f};

    for (int k0 = 0; k0 < K; k0 += 2 * TKK) {
        #pragma unroll
        for (int h = 0; h < 2; ++h) {
            const int kk = k0 + h * TKK;
            #pragma unroll
            for (int it = 0; it < 2; ++it) {
                const int chunk = it * 4 + wave;
                const int r = chunk * 16 + sr;
                __builtin_amdgcn_global_load_lds(
                    (glob_short*)(A + (long long)(m0 + r) * K + kk + sc),
                    (lds_short*)(As[h] + chunk * 512), 16, 0, 0);
                __builtin_amdgcn_global_load_lds(
                    (glob_short*)(B + (long long)(n0 + r) * K + kk + sc),
                    (lds_short*)(Bs[h] + chunk * 512), 16, 0, 0);
            }
        }
        __syncthreads();
        #pragma unroll
        for (int h = 0; h < 2; ++h) {
            bf16x8 af[4], bfr[4];
            #pragma unroll
            for (int i = 0; i < 4; ++i)
                af[i] = *(const bf16x8*)&As[h][(wm + i * 16 + (lane & 15)) * TKK + fc];
            #pragma unroll
            for (int j = 0; j < 4; ++j)
                bfr[j] = *(const bf16x8*)&Bs[h][(wn + j * 16 + (lane & 15)) * TKK + fc];
            #pragma unroll
            for (int i = 0; i < 4; ++i)
                #pragma unroll
                for (int j = 0; j < 4; ++j)
                    acc[i][j] = __builtin_amdgcn_mfma_f32_16x16x32_bf16(af[i], bfr[j], acc[i][j], 0, 0, 0);
        }
        __syncthreads();
    }

    float csum[4] = {0.f, 0.f, 0.f, 0.f};
    #pragma unroll
    for (int i = 0; i < 4; ++i) {
        const int rbase = wm + i * 16 + (lane >> 4) * 4;
        #pragma unroll
        for (int j = 0; j < 4; ++j) {
            const int col = wn + j * 16 + (lane & 15);
            #pragma unroll
            for (int r = 0; r < 4; ++r) {
                const float e = exp2_fast(acc[i][j][r]);
                E[(long long)(m0 + rbase + r) * N + (n0 + col)] = f2bf(e);
                csum[j] += e;
            }
        }
    }
    #pragma unroll
    for (int j = 0; j < 4; ++j) {
        csum[j] += __shfl_xor(csum[j], 16);
        csum[j] += __shfl_xor(csum[j], 32);
    }
    if (lane < 16) {
        #pragma unroll
        for (int j = 0; j < 4; ++j)
            wsum[wave][j * 16 + lane] = csum[j];
    }
    __syncthreads();
    if (t < 128) {
        const float s = (t < 64) ? (wsum[0][t] + wsum[2][t])
                                 : (wsum[1][t - 64] + wsum[3][t - 64]);
        atomicAdd(&colsum[n0 + t], s);
    }
}

// ---- bf16 transpose + per-row scale: out[c][r] = in[r][c] / colsum[r] ----
__global__ __launch_bounds__(256) void transpose_scale_bf16(
    const short* __restrict__ in, const float* __restrict__ colsum,
    short* __restrict__ out, int R, int Cc)
{
    __shared__ short tile[32][33];
    const int b = blockIdx.z;
    in  += (long long)b * R * Cc;
    out += (long long)b * R * Cc;
    colsum += (long long)b * R;
    const int c0 = blockIdx.x * 32, r0 = blockIdx.y * 32;
    const int tx = threadIdx.x & 31, ty = threadIdx.x >> 5;
    #pragma unroll
    for (int rr = ty; rr < 32; rr += 8) {
        const float rs = 1.f / colsum[r0 + rr];
        tile[rr][tx] = f2bf(bf2f(in[(long long)(r0 + rr) * Cc + c0 + tx]) * rs);
    }
    __syncthreads();
    #pragma unroll
    for (int rr = ty; rr < 32; rr += 8)
        out[(long long)(c0 + rr) * R + r0 + tx] = tile[tx][rr];
}

extern "C" void kernel_launch(void* const* d_in, const int* in_sizes, int n_in,
                              void* d_out, int out_size, void* d_ws, size_t ws_size,
                              hipStream_t stream) {
    const float* q  = (const float*)d_in[0];
    const float* k  = (const float*)d_in[1];
    const float* v  = (const float*)d_in[2];
    const float* Wq = (const float*)d_in[3];
    const float* bq = (const float*)d_in[4];
    const float* Wk = (const float*)d_in[5];
    const float* bk = (const float*)d_in[6];
    const float* Wv = (const float*)d_in[7];
    const float* bv = (const float*)d_in[8];
    float* out = (float*)d_out;

    const int Bb = 8, L = 2048, D = 512;
    const long long BLD = (long long)Bb * L * D;   // 8,388,608
    const long long BLL = (long long)Bb * L * L;   // 33,554,432
    const long long DD  = (long long)D * D;

    // ---- workspace layout (shorts unless noted) ----
    short* base  = (short*)d_ws;
    short* q_bf  = base;                 // BLD
    short* k_bf  = q_bf  + BLD;         // BLD
    short* v_bf  = k_bf  + BLD;         // BLD
    short* qp_bf = v_bf  + BLD;         // BLD
    short* kp_bf = qp_bf + BLD;         // BLD
    short* vp_bf = kp_bf + BLD;         // BLD
    short* vpT   = vp_bf + BLD;         // BLD
    short* Wq_bf = vpT   + BLD;         // DD
    short* Wk_bf = Wq_bf + DD;          // DD
    short* Wv_bf = Wk_bf + DD;          // DD
    short* E_bf  = Wv_bf + DD;          // BLL shorts
    float* colsum = (float*)(E_bf + BLL); // B*L floats

    dim3 blk(256);

    // 1) fused casts + colsum zero (12736 blocks)
    prep<<<dim3(12736), blk, 0, stream>>>(q, k, v, Wq, Wk, Wv,
                                          q_bf, k_bf, v_bf,
                                          Wq_bf, Wk_bf, Wv_bf, colsum);

    // 2) fused projections: M=B*L=16384, N=D=512, K=D=512, out bf16
    dim3 gproj((Bb * L) / 128, D / 128, 3);
    proj_gemm<<<gproj, blk, 0, stream>>>(q_bf, k_bf, v_bf,
                                         Wq_bf, Wk_bf, Wv_bf,
                                         bq, bk, bv,
                                         qp_bf, kp_bf, vp_bf, D, D);

    // 3) E = exp2(qp @ kp^T), colsum[b,j] = sum_i E[b,i,j]   (M=N=L, K=D)
    dim3 gS(L / 128, L / 128, Bb);
    gemm_nt_exp_colsum<<<gS, blk, 0, stream>>>(qp_bf, kp_bf, E_bf, colsum,
                                               L, D,
                                               (long long)L * D, (long long)L * D,
                                               (long long)L * L);

    // 4) vpT[d][j] = vp[j][d] / colsum[j]  per batch
    dim3 gT(D / 32, L / 32, Bb);
    transpose_scale_bf16<<<gT, blk, 0, stream>>>(vp_bf, colsum, vpT, L, D);

    // 5) out = E @ vpT^T : M=L (128-tiles), N=D (64-tiles), K=L
    dim3 gO(L / 128, D / 64, Bb);
    pv_gemm<<<gO, blk, 0, stream>>>(E_bf, vpT, out, D, L,
                                    (long long)L * L, (long long)D * L,
                                    (long long)L * D);
}

// Round 10
// 301.728 us; speedup vs baseline: 1.0567x; 1.0567x over previous
//
#include <hip/hip_runtime.h>
#include <math.h>

// B=8, L=2048, D=512, fp32 in/out. bf16 MFMA GEMMs. Column-softmax
// (axis=1 = query axis i): colsum[j]=sum_i exp(S[i,j]); out = exp(S) @ (vp/colsum).
// R1: qp pre-scaled by log2(e); S kernel uses exp2 (v_exp_f32).
// R3: LDS XOR-swizzle (col16B ^= (row>>1)&3); bank conflicts 6.3M -> 0.
// R4/R5/R8 LESSON: ALL partial-pipelining variants on the 2-barrier
//     structure (prefetch-under-syncthreads, counted-vmcnt coarse split)
//     are neutral-to-negative - matches the documented m97-ceiling /
//     m196 coarse-split result. 2-barrier R3 loop is the keeper.
// R6/R7 LESSON: f32-direct proj is latency-bound regardless of issue order.
// R9: pv only: 4 waves -> 8 waves (512 thr), waves 4m x 2n, 32x32/wave.
//     Same LDS/tile/barrier structure; resident waves 16 -> 32 per CU to
//     overlap the per-block barrier drains (occupancy was 32%).

#define TKK 32

typedef __attribute__((ext_vector_type(8))) short bf16x8;
typedef __attribute__((ext_vector_type(4))) float floatx4;

typedef __attribute__((address_space(3))) short lds_short;
typedef const __attribute__((address_space(1))) short glob_short;

__device__ __forceinline__ short f2bf(float x) {
    unsigned u = __float_as_uint(x);
    u += 0x7fff + ((u >> 16) & 1);   // round-to-nearest-even
    return (short)(u >> 16);
}
__device__ __forceinline__ float bf2f(short s) {
    return __uint_as_float(((unsigned)(unsigned short)s) << 16);
}
__device__ __forceinline__ float exp2_fast(float x) {
    float r;
    asm("v_exp_f32 %0, %1" : "=v"(r) : "v"(x));
    return r;
}

// Stage-side swizzled column (shorts): sr = lane>>2, unit = lane&3,
// swz = (lane>>3)&3 (row-within-chunk >>1).
#define STAGE_SC(lane) ((((lane) & 3) ^ (((lane) >> 3) & 3)) * 8)
// Read-side swizzled fragment column (shorts): h = lane>>4, s(row)=(lane>>1)&3.
#define FRAG_FC(lane) (((((lane) >> 4) ^ (((lane) >> 1) & 3))) * 8)

// ---- fused prep: cast q/k/v (3*4096 blocks), cast W's (3*128), zero colsum (64)
__global__ __launch_bounds__(256) void prep(
    const float* __restrict__ q, const float* __restrict__ k,
    const float* __restrict__ v,
    const float* __restrict__ Wq, const float* __restrict__ Wk,
    const float* __restrict__ Wv,
    short* __restrict__ q_bf, short* __restrict__ k_bf, short* __restrict__ v_bf,
    short* __restrict__ Wq_bf, short* __restrict__ Wk_bf, short* __restrict__ Wv_bf,
    float* __restrict__ colsum)
{
    const int b = blockIdx.x;
    const float* in = nullptr;
    short* out = nullptr;
    long long i;
    if (b < 12288) {
        const int z = b >> 12;
        in  = (z == 0) ? q    : (z == 1) ? k    : v;
        out = (z == 0) ? q_bf : (z == 1) ? k_bf : v_bf;
        i = ((long long)(b & 4095) * 256 + threadIdx.x) * 8;
    } else if (b < 12672) {
        const int z = (b - 12288) >> 7;
        in  = (z == 0) ? Wq    : (z == 1) ? Wk    : Wv;
        out = (z == 0) ? Wq_bf : (z == 1) ? Wk_bf : Wv_bf;
        i = ((long long)((b - 12288) & 127) * 256 + threadIdx.x) * 8;
    } else {
        colsum[(b - 12672) * 256 + threadIdx.x] = 0.f;
        return;
    }
    float4 x = *(const float4*)(in + i);
    float4 y = *(const float4*)(in + i + 4);
    bf16x8 r;
    r[0] = f2bf(x.x); r[1] = f2bf(x.y); r[2] = f2bf(x.z); r[3] = f2bf(x.w);
    r[4] = f2bf(y.x); r[5] = f2bf(y.y); r[6] = f2bf(y.z); r[7] = f2bf(y.w);
    *(bf16x8*)(out + i) = r;
}

// ---------------- generic NT MFMA gemm body (R3 structure) ----------------
// C[m,n] = (sum_k A[m,k]*B[n,k] + bias[n]) * escale; A:[M][K], B:[N][K] bf16.
template<int TMp, int TNp, int WM, int WN, int HAS_BIAS, int OUT_BF16>
__device__ __forceinline__ void gemm_body(
    const short* __restrict__ A, const short* __restrict__ B,
    const float* __restrict__ bias, void* __restrict__ C,
    int N, int K, int m0, int n0, float escale)
{
    __shared__ short As[TMp * TKK];
    __shared__ short Bs[TNp * TKK];
    constexpr int MI = TMp / (16 * WM);
    constexpr int NJ = TNp / (16 * WN);
    const int t    = threadIdx.x;
    const int wave = t >> 6;
    const int lane = t & 63;
    const int wm = (wave / WN) * (TMp / WM);
    const int wn = (wave % WN) * (TNp / WN);
    const int sr = lane >> 2;
    const int sc = STAGE_SC(lane);
    const int fc = FRAG_FC(lane);

    floatx4 acc[MI][NJ];
    #pragma unroll
    for (int i = 0; i < MI; ++i)
        #pragma unroll
        for (int j = 0; j < NJ; ++j)
            acc[i][j] = (floatx4){0.f, 0.f, 0.f, 0.f};

    for (int k0 = 0; k0 < K; k0 += TKK) {
        #pragma unroll
        for (int c = wave; c < TMp / 16; c += 4)
            __builtin_amdgcn_global_load_lds(
                (glob_short*)(A + (long long)(m0 + c * 16 + sr) * K + k0 + sc),
                (lds_short*)(As + c * 512), 16, 0, 0);
        #pragma unroll
        for (int c = wave; c < TNp / 16; c += 4)
            __builtin_amdgcn_global_load_lds(
                (glob_short*)(B + (long long)(n0 + c * 16 + sr) * K + k0 + sc),
                (lds_short*)(Bs + c * 512), 16, 0, 0);
        __syncthreads();
        bf16x8 af[MI], bfr[NJ];
        #pragma unroll
        for (int i = 0; i < MI; ++i)
            af[i] = *(const bf16x8*)&As[(wm + i * 16 + (lane & 15)) * TKK + fc];
        #pragma unroll
        for (int j = 0; j < NJ; ++j)
            bfr[j] = *(const bf16x8*)&Bs[(wn + j * 16 + (lane & 15)) * TKK + fc];
        #pragma unroll
        for (int i = 0; i < MI; ++i)
            #pragma unroll
            for (int j = 0; j < NJ; ++j)
                acc[i][j] = __builtin_amdgcn_mfma_f32_16x16x32_bf16(af[i], bfr[j], acc[i][j], 0, 0, 0);
        __syncthreads();
    }

    // Epilogue: C/D layout col=lane&15, row=(lane>>4)*4+reg (m89-verified)
    #pragma unroll
    for (int i = 0; i < MI; ++i) {
        const int rbase = m0 + wm + i * 16 + (lane >> 4) * 4;
        #pragma unroll
        for (int j = 0; j < NJ; ++j) {
            const int col = n0 + wn + j * 16 + (lane & 15);
            const float bb = HAS_BIAS ? bias[col] : 0.f;
            #pragma unroll
            for (int r = 0; r < 4; ++r) {
                const long long off = (long long)(rbase + r) * N + col;
                const float vvv = (acc[i][j][r] + bb) * escale;
                if (OUT_BF16) ((short*)C)[off] = f2bf(vvv);
                else          ((float*)C)[off] = vvv;
            }
        }
    }
}

// ---- fused projections: z in {0,1,2} selects (x, W, bias, out) ----
__global__ __launch_bounds__(256) void proj_gemm(
    const short* __restrict__ x0, const short* __restrict__ x1, const short* __restrict__ x2,
    const short* __restrict__ w0, const short* __restrict__ w1, const short* __restrict__ w2,
    const float* __restrict__ b0, const float* __restrict__ b1, const float* __restrict__ b2,
    short* __restrict__ y0, short* __restrict__ y1, short* __restrict__ y2,
    int N, int K)
{
    const int z = blockIdx.z;
    const short* A    = (z == 0) ? x0 : (z == 1) ? x1 : x2;
    const short* B    = (z == 0) ? w0 : (z == 1) ? w1 : w2;
    const float* bias = (z == 0) ? b0 : (z == 1) ? b1 : b2;
    short*       C    = (z == 0) ? y0 : (z == 1) ? y1 : y2;
    const float esc   = (z == 0) ? 1.4426950408889634f : 1.0f;
    gemm_body<128, 128, 2, 2, 1, 1>(A, B, bias, C, N, K,
                                    blockIdx.x * 128, blockIdx.y * 128, esc);
}

// ---- PV gemm: out = E @ vpT^T ----
// R9: 128x64 tile, 8 waves (512 thr), waves 4m x 2n (32x32 output each).
// Same 2-barrier 64-K round as R3; LDS 24 KB; grid 1024 -> 32 waves/CU.
__global__ __launch_bounds__(512) void pv_gemm(
    const short* __restrict__ Eg, const short* __restrict__ vpTg,
    float* __restrict__ outg, int N, int K,
    long long sA, long long sB, long long sC)
{
    __shared__ short As[2][128 * TKK];
    __shared__ short Bs[2][64 * TKK];
    const int bz = blockIdx.z;
    const short* A = Eg   + (long long)bz * sA;
    const short* B = vpTg + (long long)bz * sB;
    float*       C = outg + (long long)bz * sC;

    const int m0 = blockIdx.x * 128;
    const int n0 = blockIdx.y * 64;
    const int t    = threadIdx.x;
    const int wave = t >> 6;           // 0..7
    const int lane = t & 63;
    const int wm = (wave >> 1) * 32;   // 4 m-subtiles of 32 rows
    const int wn = (wave & 1)  * 32;   // 2 n-subtiles of 32 cols
    const int sr = lane >> 2;
    const int sc = STAGE_SC(lane);
    const int fc = FRAG_FC(lane);

    floatx4 acc[2][2];
    #pragma unroll
    for (int i = 0; i < 2; ++i)
        #pragma unroll
        for (int j = 0; j < 2; ++j)
            acc[i][j] = (floatx4){0.f, 0.f, 0.f, 0.f};

    for (int k0 = 0; k0 < K; k0 += 2 * TKK) {
        #pragma unroll
        for (int h = 0; h < 2; ++h) {
            const int kk = k0 + h * TKK;
            // A: 8 chunks of 16 rows, one per wave
            __builtin_amdgcn_global_load_lds(
                (glob_short*)(A + (long long)(m0 + wave * 16 + sr) * K + kk + sc),
                (lds_short*)(As[h] + wave * 512), 16, 0, 0);
            // B: 4 chunks, waves 0..3
            if (wave < 4)
                __builtin_amdgcn_global_load_lds(
                    (glob_short*)(B + (long long)(n0 + wave * 16 + sr) * K + kk + sc),
                    (lds_short*)(Bs[h] + wave * 512), 16, 0, 0);
        }
        __syncthreads();
        #pragma unroll
        for (int h = 0; h < 2; ++h) {
            bf16x8 af[2], bfr[2];
            #pragma unroll
            for (int i = 0; i < 2; ++i)
                af[i] = *(const bf16x8*)&As[h][(wm + i * 16 + (lane & 15)) * TKK + fc];
            #pragma unroll
            for (int j = 0; j < 2; ++j)
                bfr[j] = *(const bf16x8*)&Bs[h][(wn + j * 16 + (lane & 15)) * TKK + fc];
            #pragma unroll
            for (int i = 0; i < 2; ++i)
                #pragma unroll
                for (int j = 0; j < 2; ++j)
                    acc[i][j] = __builtin_amdgcn_mfma_f32_16x16x32_bf16(af[i], bfr[j], acc[i][j], 0, 0, 0);
        }
        __syncthreads();
    }

    #pragma unroll
    for (int i = 0; i < 2; ++i) {
        const int rbase = m0 + wm + i * 16 + (lane >> 4) * 4;
        #pragma unroll
        for (int j = 0; j < 2; ++j) {
            const int col = n0 + wn + j * 16 + (lane & 15);
            #pragma unroll
            for (int r = 0; r < 4; ++r)
                C[(long long)(rbase + r) * N + col] = acc[i][j][r];
        }
    }
}

// ---- NT MFMA gemm with fused exp2 + column-sum (exact R3 structure) ----
__global__ __launch_bounds__(256) void gemm_nt_exp_colsum(
    const short* __restrict__ A, const short* __restrict__ B,
    short* __restrict__ E, float* __restrict__ colsum,
    int N, int K, long long sA, long long sB, long long sE)
{
    __shared__ short As[2][128 * TKK];
    __shared__ short Bs[2][128 * TKK];
    __shared__ float wsum[4][64];
    const int bz = blockIdx.z;
    A += (long long)bz * sA;
    B += (long long)bz * sB;
    E += (long long)bz * sE;
    colsum += (long long)bz * N;

    const int m0 = blockIdx.x * 128;
    const int n0 = blockIdx.y * 128;
    const int t    = threadIdx.x;
    const int wave = t >> 6;
    const int lane = t & 63;
    const int wm = (wave >> 1) * 64;
    const int wn = (wave & 1)  * 64;
    const int sr = lane >> 2;
    const int sc = STAGE_SC(lane);
    const int fc = FRAG_FC(lane);

    floatx4 acc[4][4];
    #pragma unroll
    for (int i = 0; i < 4; ++i)
        #pragma unroll
        for (int j = 0; j < 4; ++j)
            acc[i][j] = (floatx4){0.f, 0.f, 0.f, 0.f};

    for (int k0 = 0; k0 < K; k0 += 2 * TKK) {
        #pragma unroll
        for (int h = 0; h < 2; ++h) {
            const int kk = k0 + h * TKK;
            #pragma unroll
            for (int it = 0; it < 2; ++it) {
                const int chunk = it * 4 + wave;
                const int r = chunk * 16 + sr;
                __builtin_amdgcn_global_load_lds(
                    (glob_short*)(A + (long long)(m0 + r) * K + kk + sc),
                    (lds_short*)(As[h] + chunk * 512), 16, 0, 0);
                __builtin_amdgcn_global_load_lds(
                    (glob_short*)(B + (long long)(n0 + r) * K + kk + sc),
                    (lds_short*)(Bs[h] + chunk * 512), 16, 0, 0);
            }
        }
        __syncthreads();
        #pragma unroll
        for (int h = 0; h < 2; ++h) {
            bf16x8 af[4], bfr[4];
            #pragma unroll
            for (int i = 0; i < 4; ++i)
                af[i] = *(const bf16x8*)&As[h][(wm + i * 16 + (lane & 15)) * TKK + fc];
            #pragma unroll
            for (int j = 0; j < 4; ++j)
                bfr[j] = *(const bf16x8*)&Bs[h][(wn + j * 16 + (lane & 15)) * TKK + fc];
            #pragma unroll
            for (int i = 0; i < 4; ++i)
                #pragma unroll
                for (int j = 0; j < 4; ++j)
                    acc[i][j] = __builtin_amdgcn_mfma_f32_16x16x32_bf16(af[i], bfr[j], acc[i][j], 0, 0, 0);
        }
        __syncthreads();
    }

    float csum[4] = {0.f, 0.f, 0.f, 0.f};
    #pragma unroll
    for (int i = 0; i < 4; ++i) {
        const int rbase = wm + i * 16 + (lane >> 4) * 4;
        #pragma unroll
        for (int j = 0; j < 4; ++j) {
            const int col = wn + j * 16 + (lane & 15);
            #pragma unroll
            for (int r = 0; r < 4; ++r) {
                const float e = exp2_fast(acc[i][j][r]);
                E[(long long)(m0 + rbase + r) * N + (n0 + col)] = f2bf(e);
                csum[j] += e;
            }
        }
    }
    #pragma unroll
    for (int j = 0; j < 4; ++j) {
        csum[j] += __shfl_xor(csum[j], 16);
        csum[j] += __shfl_xor(csum[j], 32);
    }
    if (lane < 16) {
        #pragma unroll
        for (int j = 0; j < 4; ++j)
            wsum[wave][j * 16 + lane] = csum[j];
    }
    __syncthreads();
    if (t < 128) {
        const float s = (t < 64) ? (wsum[0][t] + wsum[2][t])
                                 : (wsum[1][t - 64] + wsum[3][t - 64]);
        atomicAdd(&colsum[n0 + t], s);
    }
}

// ---- bf16 transpose + per-row scale: out[c][r] = in[r][c] / colsum[r] ----
__global__ __launch_bounds__(256) void transpose_scale_bf16(
    const short* __restrict__ in, const float* __restrict__ colsum,
    short* __restrict__ out, int R, int Cc)
{
    __shared__ short tile[32][33];
    const int b = blockIdx.z;
    in  += (long long)b * R * Cc;
    out += (long long)b * R * Cc;
    colsum += (long long)b * R;
    const int c0 = blockIdx.x * 32, r0 = blockIdx.y * 32;
    const int tx = threadIdx.x & 31, ty = threadIdx.x >> 5;
    #pragma unroll
    for (int rr = ty; rr < 32; rr += 8) {
        const float rs = 1.f / colsum[r0 + rr];
        tile[rr][tx] = f2bf(bf2f(in[(long long)(r0 + rr) * Cc + c0 + tx]) * rs);
    }
    __syncthreads();
    #pragma unroll
    for (int rr = ty; rr < 32; rr += 8)
        out[(long long)(c0 + rr) * R + r0 + tx] = tile[tx][rr];
}

extern "C" void kernel_launch(void* const* d_in, const int* in_sizes, int n_in,
                              void* d_out, int out_size, void* d_ws, size_t ws_size,
                              hipStream_t stream) {
    const float* q  = (const float*)d_in[0];
    const float* k  = (const float*)d_in[1];
    const float* v  = (const float*)d_in[2];
    const float* Wq = (const float*)d_in[3];
    const float* bq = (const float*)d_in[4];
    const float* Wk = (const float*)d_in[5];
    const float* bk = (const float*)d_in[6];
    const float* Wv = (const float*)d_in[7];
    const float* bv = (const float*)d_in[8];
    float* out = (float*)d_out;

    const int Bb = 8, L = 2048, D = 512;
    const long long BLD = (long long)Bb * L * D;   // 8,388,608
    const long long BLL = (long long)Bb * L * L;   // 33,554,432
    const long long DD  = (long long)D * D;

    // ---- workspace layout (shorts unless noted) ----
    short* base  = (short*)d_ws;
    short* q_bf  = base;                 // BLD
    short* k_bf  = q_bf  + BLD;         // BLD
    short* v_bf  = k_bf  + BLD;         // BLD
    short* qp_bf = v_bf  + BLD;         // BLD
    short* kp_bf = qp_bf + BLD;         // BLD
    short* vp_bf = kp_bf + BLD;         // BLD
    short* vpT   = vp_bf + BLD;         // BLD
    short* Wq_bf = vpT   + BLD;         // DD
    short* Wk_bf = Wq_bf + DD;          // DD
    short* Wv_bf = Wk_bf + DD;          // DD
    short* E_bf  = Wv_bf + DD;          // BLL shorts
    float* colsum = (float*)(E_bf + BLL); // B*L floats

    dim3 blk(256);

    // 1) fused casts + colsum zero (12736 blocks)
    prep<<<dim3(12736), blk, 0, stream>>>(q, k, v, Wq, Wk, Wv,
                                          q_bf, k_bf, v_bf,
                                          Wq_bf, Wk_bf, Wv_bf, colsum);

    // 2) fused projections: M=B*L=16384, N=D=512, K=D=512, out bf16
    dim3 gproj((Bb * L) / 128, D / 128, 3);
    proj_gemm<<<gproj, blk, 0, stream>>>(q_bf, k_bf, v_bf,
                                         Wq_bf, Wk_bf, Wv_bf,
                                         bq, bk, bv,
                                         qp_bf, kp_bf, vp_bf, D, D);

    // 3) E = exp2(qp @ kp^T), colsum[b,j] = sum_i E[b,i,j]   (M=N=L, K=D)
    dim3 gS(L / 128, L / 128, Bb);
    gemm_nt_exp_colsum<<<gS, blk, 0, stream>>>(qp_bf, kp_bf, E_bf, colsum,
                                               L, D,
                                               (long long)L * D, (long long)L * D,
                                               (long long)L * L);

    // 4) vpT[d][j] = vp[j][d] / colsum[j]  per batch
    dim3 gT(D / 32, L / 32, Bb);
    transpose_scale_bf16<<<gT, blk, 0, stream>>>(vp_bf, colsum, vpT, L, D);

    // 5) out = E @ vpT^T : M=L (128-tiles), N=D (64-tiles), K=L, 512 thr
    dim3 gO(L / 128, D / 64, Bb);
    pv_gemm<<<gO, dim3(512), 0, stream>>>(E_bf, vpT, out, D, L,
                                          (long long)L * L, (long long)D * L,
                                          (long long)L * D);
}

// Round 11
// 301.613 us; speedup vs baseline: 1.0571x; 1.0004x over previous
//
#include <hip/hip_runtime.h>
#include <math.h>

// B=8, L=2048, D=512, fp32 in/out. bf16 MFMA GEMMs. Column-softmax
// (axis=1 = query axis i): colsum[j]=sum_i exp(S[i,j]); out = exp(S) @ (vp/colsum).
// R1: qp pre-scaled by log2(e); S kernel uses exp2 (v_exp_f32).
// R3: LDS XOR-swizzle (col16B ^= (row>>1)&3); bank conflicts 6.3M -> 0.
// R4/R5/R8 LESSON: partial pipelining on the 2-barrier structure is
//     neutral-to-negative (matches documented m97-ceiling / m196).
// R6/R7 LESSON: f32-direct proj is latency-bound regardless of issue order.
// R9: pv 4->8 waves (512 thr): occupancy 32->60%, 60.5->58.5us. VERIFIED.
// R10: propagate 8-wave to S and proj (same transformation): waves 4m x 2n,
//      32x64 output/wave, acc 2x4; S epilogue halves per-thread (64->32
//      exp2+store). colsum reduction reworked for 8 waves.

#define TKK 32

typedef __attribute__((ext_vector_type(8))) short bf16x8;
typedef __attribute__((ext_vector_type(4))) float floatx4;

typedef __attribute__((address_space(3))) short lds_short;
typedef const __attribute__((address_space(1))) short glob_short;

__device__ __forceinline__ short f2bf(float x) {
    unsigned u = __float_as_uint(x);
    u += 0x7fff + ((u >> 16) & 1);   // round-to-nearest-even
    return (short)(u >> 16);
}
__device__ __forceinline__ float bf2f(short s) {
    return __uint_as_float(((unsigned)(unsigned short)s) << 16);
}
__device__ __forceinline__ float exp2_fast(float x) {
    float r;
    asm("v_exp_f32 %0, %1" : "=v"(r) : "v"(x));
    return r;
}

// Stage-side swizzled column (shorts): sr = lane>>2, unit = lane&3,
// swz = (lane>>3)&3 (row-within-chunk >>1).
#define STAGE_SC(lane) ((((lane) & 3) ^ (((lane) >> 3) & 3)) * 8)
// Read-side swizzled fragment column (shorts): h = lane>>4, s(row)=(lane>>1)&3.
#define FRAG_FC(lane) (((((lane) >> 4) ^ (((lane) >> 1) & 3))) * 8)

// ---- fused prep: cast q/k/v (3*4096 blocks), cast W's (3*128), zero colsum (64)
__global__ __launch_bounds__(256) void prep(
    const float* __restrict__ q, const float* __restrict__ k,
    const float* __restrict__ v,
    const float* __restrict__ Wq, const float* __restrict__ Wk,
    const float* __restrict__ Wv,
    short* __restrict__ q_bf, short* __restrict__ k_bf, short* __restrict__ v_bf,
    short* __restrict__ Wq_bf, short* __restrict__ Wk_bf, short* __restrict__ Wv_bf,
    float* __restrict__ colsum)
{
    const int b = blockIdx.x;
    const float* in = nullptr;
    short* out = nullptr;
    long long i;
    if (b < 12288) {
        const int z = b >> 12;
        in  = (z == 0) ? q    : (z == 1) ? k    : v;
        out = (z == 0) ? q_bf : (z == 1) ? k_bf : v_bf;
        i = ((long long)(b & 4095) * 256 + threadIdx.x) * 8;
    } else if (b < 12672) {
        const int z = (b - 12288) >> 7;
        in  = (z == 0) ? Wq    : (z == 1) ? Wk    : Wv;
        out = (z == 0) ? Wq_bf : (z == 1) ? Wk_bf : Wv_bf;
        i = ((long long)((b - 12288) & 127) * 256 + threadIdx.x) * 8;
    } else {
        colsum[(b - 12672) * 256 + threadIdx.x] = 0.f;
        return;
    }
    float4 x = *(const float4*)(in + i);
    float4 y = *(const float4*)(in + i + 4);
    bf16x8 r;
    r[0] = f2bf(x.x); r[1] = f2bf(x.y); r[2] = f2bf(x.z); r[3] = f2bf(x.w);
    r[4] = f2bf(y.x); r[5] = f2bf(y.y); r[6] = f2bf(y.z); r[7] = f2bf(y.w);
    *(bf16x8*)(out + i) = r;
}

// ---------------- generic NT MFMA gemm body (R3 structure, N-wave) ----------
// C[m,n] = (sum_k A[m,k]*B[n,k] + bias[n]) * escale; A:[M][K], B:[N][K] bf16.
template<int TMp, int TNp, int WM, int WN, int HAS_BIAS, int OUT_BF16>
__device__ __forceinline__ void gemm_body(
    const short* __restrict__ A, const short* __restrict__ B,
    const float* __restrict__ bias, void* __restrict__ C,
    int N, int K, int m0, int n0, float escale)
{
    __shared__ short As[TMp * TKK];
    __shared__ short Bs[TNp * TKK];
    constexpr int MI = TMp / (16 * WM);
    constexpr int NJ = TNp / (16 * WN);
    constexpr int NWAVES = WM * WN;
    const int t    = threadIdx.x;
    const int wave = t >> 6;
    const int lane = t & 63;
    const int wm = (wave / WN) * (TMp / WM);
    const int wn = (wave % WN) * (TNp / WN);
    const int sr = lane >> 2;
    const int sc = STAGE_SC(lane);
    const int fc = FRAG_FC(lane);

    floatx4 acc[MI][NJ];
    #pragma unroll
    for (int i = 0; i < MI; ++i)
        #pragma unroll
        for (int j = 0; j < NJ; ++j)
            acc[i][j] = (floatx4){0.f, 0.f, 0.f, 0.f};

    for (int k0 = 0; k0 < K; k0 += TKK) {
        #pragma unroll
        for (int c = wave; c < TMp / 16; c += NWAVES)
            __builtin_amdgcn_global_load_lds(
                (glob_short*)(A + (long long)(m0 + c * 16 + sr) * K + k0 + sc),
                (lds_short*)(As + c * 512), 16, 0, 0);
        #pragma unroll
        for (int c = wave; c < TNp / 16; c += NWAVES)
            __builtin_amdgcn_global_load_lds(
                (glob_short*)(B + (long long)(n0 + c * 16 + sr) * K + k0 + sc),
                (lds_short*)(Bs + c * 512), 16, 0, 0);
        __syncthreads();
        bf16x8 af[MI], bfr[NJ];
        #pragma unroll
        for (int i = 0; i < MI; ++i)
            af[i] = *(const bf16x8*)&As[(wm + i * 16 + (lane & 15)) * TKK + fc];
        #pragma unroll
        for (int j = 0; j < NJ; ++j)
            bfr[j] = *(const bf16x8*)&Bs[(wn + j * 16 + (lane & 15)) * TKK + fc];
        #pragma unroll
        for (int i = 0; i < MI; ++i)
            #pragma unroll
            for (int j = 0; j < NJ; ++j)
                acc[i][j] = __builtin_amdgcn_mfma_f32_16x16x32_bf16(af[i], bfr[j], acc[i][j], 0, 0, 0);
        __syncthreads();
    }

    // Epilogue: C/D layout col=lane&15, row=(lane>>4)*4+reg (m89-verified)
    #pragma unroll
    for (int i = 0; i < MI; ++i) {
        const int rbase = m0 + wm + i * 16 + (lane >> 4) * 4;
        #pragma unroll
        for (int j = 0; j < NJ; ++j) {
            const int col = n0 + wn + j * 16 + (lane & 15);
            const float bb = HAS_BIAS ? bias[col] : 0.f;
            #pragma unroll
            for (int r = 0; r < 4; ++r) {
                const long long off = (long long)(rbase + r) * N + col;
                const float vvv = (acc[i][j][r] + bb) * escale;
                if (OUT_BF16) ((short*)C)[off] = f2bf(vvv);
                else          ((float*)C)[off] = vvv;
            }
        }
    }
}

// ---- fused projections: z in {0,1,2} selects (x, W, bias, out) ----
// R10: 8 waves (512 thr), waves 4m x 2n.
__global__ __launch_bounds__(512) void proj_gemm(
    const short* __restrict__ x0, const short* __restrict__ x1, const short* __restrict__ x2,
    const short* __restrict__ w0, const short* __restrict__ w1, const short* __restrict__ w2,
    const float* __restrict__ b0, const float* __restrict__ b1, const float* __restrict__ b2,
    short* __restrict__ y0, short* __restrict__ y1, short* __restrict__ y2,
    int N, int K)
{
    const int z = blockIdx.z;
    const short* A    = (z == 0) ? x0 : (z == 1) ? x1 : x2;
    const short* B    = (z == 0) ? w0 : (z == 1) ? w1 : w2;
    const float* bias = (z == 0) ? b0 : (z == 1) ? b1 : b2;
    short*       C    = (z == 0) ? y0 : (z == 1) ? y1 : y2;
    const float esc   = (z == 0) ? 1.4426950408889634f : 1.0f;
    gemm_body<128, 128, 4, 2, 1, 1>(A, B, bias, C, N, K,
                                    blockIdx.x * 128, blockIdx.y * 128, esc);
}

// ---- PV gemm: out = E @ vpT^T ---- (R9 structure, unchanged)
// 128x64 tile, 8 waves (512 thr), waves 4m x 2n (32x32 output each).
__global__ __launch_bounds__(512) void pv_gemm(
    const short* __restrict__ Eg, const short* __restrict__ vpTg,
    float* __restrict__ outg, int N, int K,
    long long sA, long long sB, long long sC)
{
    __shared__ short As[2][128 * TKK];
    __shared__ short Bs[2][64 * TKK];
    const int bz = blockIdx.z;
    const short* A = Eg   + (long long)bz * sA;
    const short* B = vpTg + (long long)bz * sB;
    float*       C = outg + (long long)bz * sC;

    const int m0 = blockIdx.x * 128;
    const int n0 = blockIdx.y * 64;
    const int t    = threadIdx.x;
    const int wave = t >> 6;           // 0..7
    const int lane = t & 63;
    const int wm = (wave >> 1) * 32;   // 4 m-subtiles of 32 rows
    const int wn = (wave & 1)  * 32;   // 2 n-subtiles of 32 cols
    const int sr = lane >> 2;
    const int sc = STAGE_SC(lane);
    const int fc = FRAG_FC(lane);

    floatx4 acc[2][2];
    #pragma unroll
    for (int i = 0; i < 2; ++i)
        #pragma unroll
        for (int j = 0; j < 2; ++j)
            acc[i][j] = (floatx4){0.f, 0.f, 0.f, 0.f};

    for (int k0 = 0; k0 < K; k0 += 2 * TKK) {
        #pragma unroll
        for (int h = 0; h < 2; ++h) {
            const int kk = k0 + h * TKK;
            __builtin_amdgcn_global_load_lds(
                (glob_short*)(A + (long long)(m0 + wave * 16 + sr) * K + kk + sc),
                (lds_short*)(As[h] + wave * 512), 16, 0, 0);
            if (wave < 4)
                __builtin_amdgcn_global_load_lds(
                    (glob_short*)(B + (long long)(n0 + wave * 16 + sr) * K + kk + sc),
                    (lds_short*)(Bs[h] + wave * 512), 16, 0, 0);
        }
        __syncthreads();
        #pragma unroll
        for (int h = 0; h < 2; ++h) {
            bf16x8 af[2], bfr[2];
            #pragma unroll
            for (int i = 0; i < 2; ++i)
                af[i] = *(const bf16x8*)&As[h][(wm + i * 16 + (lane & 15)) * TKK + fc];
            #pragma unroll
            for (int j = 0; j < 2; ++j)
                bfr[j] = *(const bf16x8*)&Bs[h][(wn + j * 16 + (lane & 15)) * TKK + fc];
            #pragma unroll
            for (int i = 0; i < 2; ++i)
                #pragma unroll
                for (int j = 0; j < 2; ++j)
                    acc[i][j] = __builtin_amdgcn_mfma_f32_16x16x32_bf16(af[i], bfr[j], acc[i][j], 0, 0, 0);
        }
        __syncthreads();
    }

    #pragma unroll
    for (int i = 0; i < 2; ++i) {
        const int rbase = m0 + wm + i * 16 + (lane >> 4) * 4;
        #pragma unroll
        for (int j = 0; j < 2; ++j) {
            const int col = n0 + wn + j * 16 + (lane & 15);
            #pragma unroll
            for (int r = 0; r < 4; ++r)
                C[(long long)(rbase + r) * N + col] = acc[i][j][r];
        }
    }
}

// ---- NT MFMA gemm with fused exp2 + column-sum ----
// R10: 8 waves (512 thr), waves 4m x 2n, per-wave 32x64 (acc 2x4);
// per-thread epilogue 64->32 elems; colsum reduction over 8 waves.
__global__ __launch_bounds__(512) void gemm_nt_exp_colsum(
    const short* __restrict__ A, const short* __restrict__ B,
    short* __restrict__ E, float* __restrict__ colsum,
    int N, int K, long long sA, long long sB, long long sE)
{
    __shared__ short As[2][128 * TKK];
    __shared__ short Bs[2][128 * TKK];
    __shared__ float wsum[8][64];
    const int bz = blockIdx.z;
    A += (long long)bz * sA;
    B += (long long)bz * sB;
    E += (long long)bz * sE;
    colsum += (long long)bz * N;

    const int m0 = blockIdx.x * 128;
    const int n0 = blockIdx.y * 128;
    const int t    = threadIdx.x;
    const int wave = t >> 6;           // 0..7
    const int lane = t & 63;
    const int wm = (wave >> 1) * 32;   // 4 m-subtiles of 32 rows
    const int wn = (wave & 1)  * 64;   // 2 n-subtiles of 64 cols
    const int sr = lane >> 2;
    const int sc = STAGE_SC(lane);
    const int fc = FRAG_FC(lane);

    floatx4 acc[2][4];
    #pragma unroll
    for (int i = 0; i < 2; ++i)
        #pragma unroll
        for (int j = 0; j < 4; ++j)
            acc[i][j] = (floatx4){0.f, 0.f, 0.f, 0.f};

    for (int k0 = 0; k0 < K; k0 += 2 * TKK) {
        #pragma unroll
        for (int h = 0; h < 2; ++h) {
            const int kk = k0 + h * TKK;
            const int r = wave * 16 + sr;    // one A chunk + one B chunk per wave
            __builtin_amdgcn_global_load_lds(
                (glob_short*)(A + (long long)(m0 + r) * K + kk + sc),
                (lds_short*)(As[h] + wave * 512), 16, 0, 0);
            __builtin_amdgcn_global_load_lds(
                (glob_short*)(B + (long long)(n0 + r) * K + kk + sc),
                (lds_short*)(Bs[h] + wave * 512), 16, 0, 0);
        }
        __syncthreads();
        #pragma unroll
        for (int h = 0; h < 2; ++h) {
            bf16x8 af[2], bfr[4];
            #pragma unroll
            for (int i = 0; i < 2; ++i)
                af[i] = *(const bf16x8*)&As[h][(wm + i * 16 + (lane & 15)) * TKK + fc];
            #pragma unroll
            for (int j = 0; j < 4; ++j)
                bfr[j] = *(const bf16x8*)&Bs[h][(wn + j * 16 + (lane & 15)) * TKK + fc];
            #pragma unroll
            for (int i = 0; i < 2; ++i)
                #pragma unroll
                for (int j = 0; j < 4; ++j)
                    acc[i][j] = __builtin_amdgcn_mfma_f32_16x16x32_bf16(af[i], bfr[j], acc[i][j], 0, 0, 0);
        }
        __syncthreads();
    }

    float csum[4] = {0.f, 0.f, 0.f, 0.f};
    #pragma unroll
    for (int i = 0; i < 2; ++i) {
        const int rbase = wm + i * 16 + (lane >> 4) * 4;
        #pragma unroll
        for (int j = 0; j < 4; ++j) {
            const int col = wn + j * 16 + (lane & 15);
            #pragma unroll
            for (int r = 0; r < 4; ++r) {
                const float e = exp2_fast(acc[i][j][r]);
                E[(long long)(m0 + rbase + r) * N + (n0 + col)] = f2bf(e);
                csum[j] += e;
            }
        }
    }
    // reduce the 4 row-groups (lane>>4) within the wave
    #pragma unroll
    for (int j = 0; j < 4; ++j) {
        csum[j] += __shfl_xor(csum[j], 16);
        csum[j] += __shfl_xor(csum[j], 32);
    }
    if (lane < 16) {
        #pragma unroll
        for (int j = 0; j < 4; ++j)
            wsum[wave][j * 16 + lane] = csum[j];
    }
    __syncthreads();
    // cols 0-63 owned by even waves (wn=0), 64-127 by odd waves (wn=64)
    if (t < 128) {
        const int half = t >> 6;        // wave parity
        const int col  = t & 63;
        const float s = wsum[half][col] + wsum[half + 2][col]
                      + wsum[half + 4][col] + wsum[half + 6][col];
        atomicAdd(&colsum[n0 + half * 64 + col], s);
    }
}

// ---- bf16 transpose + per-row scale: out[c][r] = in[r][c] / colsum[r] ----
__global__ __launch_bounds__(256) void transpose_scale_bf16(
    const short* __restrict__ in, const float* __restrict__ colsum,
    short* __restrict__ out, int R, int Cc)
{
    __shared__ short tile[32][33];
    const int b = blockIdx.z;
    in  += (long long)b * R * Cc;
    out += (long long)b * R * Cc;
    colsum += (long long)b * R;
    const int c0 = blockIdx.x * 32, r0 = blockIdx.y * 32;
    const int tx = threadIdx.x & 31, ty = threadIdx.x >> 5;
    #pragma unroll
    for (int rr = ty; rr < 32; rr += 8) {
        const float rs = 1.f / colsum[r0 + rr];
        tile[rr][tx] = f2bf(bf2f(in[(long long)(r0 + rr) * Cc + c0 + tx]) * rs);
    }
    __syncthreads();
    #pragma unroll
    for (int rr = ty; rr < 32; rr += 8)
        out[(long long)(c0 + rr) * R + r0 + tx] = tile[tx][rr];
}

extern "C" void kernel_launch(void* const* d_in, const int* in_sizes, int n_in,
                              void* d_out, int out_size, void* d_ws, size_t ws_size,
                              hipStream_t stream) {
    const float* q  = (const float*)d_in[0];
    const float* k  = (const float*)d_in[1];
    const float* v  = (const float*)d_in[2];
    const float* Wq = (const float*)d_in[3];
    const float* bq = (const float*)d_in[4];
    const float* Wk = (const float*)d_in[5];
    const float* bk = (const float*)d_in[6];
    const float* Wv = (const float*)d_in[7];
    const float* bv = (const float*)d_in[8];
    float* out = (float*)d_out;

    const int Bb = 8, L = 2048, D = 512;
    const long long BLD = (long long)Bb * L * D;   // 8,388,608
    const long long BLL = (long long)Bb * L * L;   // 33,554,432
    const long long DD  = (long long)D * D;

    // ---- workspace layout (shorts unless noted) ----
    short* base  = (short*)d_ws;
    short* q_bf  = base;                 // BLD
    short* k_bf  = q_bf  + BLD;         // BLD
    short* v_bf  = k_bf  + BLD;         // BLD
    short* qp_bf = v_bf  + BLD;         // BLD
    short* kp_bf = qp_bf + BLD;         // BLD
    short* vp_bf = kp_bf + BLD;         // BLD
    short* vpT   = vp_bf + BLD;         // BLD
    short* Wq_bf = vpT   + BLD;         // DD
    short* Wk_bf = Wq_bf + DD;          // DD
    short* Wv_bf = Wk_bf + DD;          // DD
    short* E_bf  = Wv_bf + DD;          // BLL shorts
    float* colsum = (float*)(E_bf + BLL); // B*L floats

    dim3 blk(256);

    // 1) fused casts + colsum zero (12736 blocks)
    prep<<<dim3(12736), blk, 0, stream>>>(q, k, v, Wq, Wk, Wv,
                                          q_bf, k_bf, v_bf,
                                          Wq_bf, Wk_bf, Wv_bf, colsum);

    // 2) fused projections: M=B*L=16384, N=D=512, K=D=512, out bf16, 512 thr
    dim3 gproj((Bb * L) / 128, D / 128, 3);
    proj_gemm<<<gproj, dim3(512), 0, stream>>>(q_bf, k_bf, v_bf,
                                               Wq_bf, Wk_bf, Wv_bf,
                                               bq, bk, bv,
                                               qp_bf, kp_bf, vp_bf, D, D);

    // 3) E = exp2(qp @ kp^T), colsum[b,j] = sum_i E[b,i,j], 512 thr
    dim3 gS(L / 128, L / 128, Bb);
    gemm_nt_exp_colsum<<<gS, dim3(512), 0, stream>>>(qp_bf, kp_bf, E_bf, colsum,
                                                     L, D,
                                                     (long long)L * D, (long long)L * D,
                                                     (long long)L * L);

    // 4) vpT[d][j] = vp[j][d] / colsum[j]  per batch
    dim3 gT(D / 32, L / 32, Bb);
    transpose_scale_bf16<<<gT, blk, 0, stream>>>(vp_bf, colsum, vpT, L, D);

    // 5) out = E @ vpT^T : M=L (128-tiles), N=D (64-tiles), K=L, 512 thr
    dim3 gO(L / 128, D / 64, Bb);
    pv_gemm<<<gO, dim3(512), 0, stream>>>(E_bf, vpT, out, D, L,
                                          (long long)L * L, (long long)D * L,
                                          (long long)L * D);
}

// Round 12
// 300.281 us; speedup vs baseline: 1.0618x; 1.0044x over previous
//
#include <hip/hip_runtime.h>
#include <math.h>

// B=8, L=2048, D=512, fp32 in/out. bf16 MFMA GEMMs. Column-softmax
// (axis=1 = query axis i): colsum[j]=sum_i exp(S[i,j]); out = exp(S) @ (vp/colsum).
// R1: qp pre-scaled by log2(e); S kernel uses exp2 (v_exp_f32).
// R3: LDS XOR-swizzle; bank conflicts 6.3M -> 0.
// R4/R5/R8: partial pipelining on 2-barrier structure = null/negative.
// R6/R7 LESSON: reg-staged f32 proj is latency-bound (79us).
// R9/R10: 8-wave (512thr) on all GEMMs: occupancy 32->60%. VERIFIED small wins.
// R11: kill the q/k/v cast round-trip (144MB, ~28us) WITHOUT reg-staging:
//      proj stages A as raw f32 via global_load_lds (proven path), casts
//      AFTER the LDS fragment read. f32 LDS layout gets its own XOR swizzle
//      (unit ^= row&7): 2-way on reads = free. prep = W casts + colsum only.

#define TKK 32

typedef __attribute__((ext_vector_type(8))) short bf16x8;
typedef __attribute__((ext_vector_type(4))) float floatx4;

typedef __attribute__((address_space(3))) short lds_short;
typedef const __attribute__((address_space(1))) short glob_short;
typedef __attribute__((address_space(3))) float lds_float;
typedef const __attribute__((address_space(1))) float glob_float;

__device__ __forceinline__ short f2bf(float x) {
    unsigned u = __float_as_uint(x);
    u += 0x7fff + ((u >> 16) & 1);   // round-to-nearest-even
    return (short)(u >> 16);
}
__device__ __forceinline__ float bf2f(short s) {
    return __uint_as_float(((unsigned)(unsigned short)s) << 16);
}
__device__ __forceinline__ float exp2_fast(float x) {
    float r;
    asm("v_exp_f32 %0, %1" : "=v"(r) : "v"(x));
    return r;
}

// bf16 tile swizzle (R3): stage source col unit and fragment read col.
#define STAGE_SC(lane) ((((lane) & 3) ^ (((lane) >> 3) & 3)) * 8)
#define FRAG_FC(lane) (((((lane) >> 4) ^ (((lane) >> 1) & 3))) * 8)

// ---- prep: cast W's (3*128 blocks) + zero colsum (64 blocks) ----
__global__ __launch_bounds__(256) void prep(
    const float* __restrict__ Wq, const float* __restrict__ Wk,
    const float* __restrict__ Wv,
    short* __restrict__ Wq_bf, short* __restrict__ Wk_bf, short* __restrict__ Wv_bf,
    float* __restrict__ colsum)
{
    const int b = blockIdx.x;
    if (b < 384) {
        const int z = b >> 7;
        const float* in = (z == 0) ? Wq : (z == 1) ? Wk : Wv;
        short* out = (z == 0) ? Wq_bf : (z == 1) ? Wk_bf : Wv_bf;
        const long long i = ((long long)(b & 127) * 256 + threadIdx.x) * 8;
        float4 x = *(const float4*)(in + i);
        float4 y = *(const float4*)(in + i + 4);
        bf16x8 r;
        r[0] = f2bf(x.x); r[1] = f2bf(x.y); r[2] = f2bf(x.z); r[3] = f2bf(x.w);
        r[4] = f2bf(y.x); r[5] = f2bf(y.y); r[6] = f2bf(y.z); r[7] = f2bf(y.w);
        *(bf16x8*)(out + i) = r;
    } else {
        colsum[(b - 384) * 256 + threadIdx.x] = 0.f;
    }
}

// ---- fused projections: f32 A staged via global_load_lds, cast post-LDS ----
// C[m,n] = (sum_k x[m,k]*W[n,k] + bias[n]) * esc, out bf16.
// 128x128 tile, 8 waves (4m x 2n), per-wave 32x128... acc 2x4 (32x64 eff).
__global__ __launch_bounds__(512) void proj_gemm(
    const float* __restrict__ x0, const float* __restrict__ x1, const float* __restrict__ x2,
    const short* __restrict__ w0, const short* __restrict__ w1, const short* __restrict__ w2,
    const float* __restrict__ b0, const float* __restrict__ b1, const float* __restrict__ b2,
    short* __restrict__ y0, short* __restrict__ y1, short* __restrict__ y2,
    int N, int K)
{
    const int z = blockIdx.z;
    const float* A    = (z == 0) ? x0 : (z == 1) ? x1 : x2;
    const short* B    = (z == 0) ? w0 : (z == 1) ? w1 : w2;
    const float* bias = (z == 0) ? b0 : (z == 1) ? b1 : b2;
    short*       C    = (z == 0) ? y0 : (z == 1) ? y1 : y2;
    const float esc   = (z == 0) ? 1.4426950408889634f : 1.0f;

    __shared__ float Asf[128 * TKK];   // f32 A tile: 16 KB
    __shared__ short Bs[128 * TKK];    // bf16 B tile: 8 KB
    const int t    = threadIdx.x;
    const int wave = t >> 6;           // 0..7
    const int lane = t & 63;
    const int wm = (wave >> 1) * 32;   // 4 m-subtiles of 32 rows
    const int wn = (wave & 1)  * 64;   // 2 n-subtiles of 64 cols
    const int sr = lane >> 2;
    const int sc = STAGE_SC(lane);
    const int fc = FRAG_FC(lane);
    const int m0 = blockIdx.x * 128;
    const int n0 = blockIdx.y * 128;
    // f32-A staging: 8 lanes/row (128B), unit = (lane&7) ^ row8 (involution)
    const int ar8 = lane >> 3;                 // row within 8-row chunk
    const int au  = ((lane & 7) ^ ar8) * 4;    // f32 col offset of this lane's 16B
    const int h   = lane >> 4;                 // fragment k-group

    floatx4 acc[2][4];
    #pragma unroll
    for (int i = 0; i < 2; ++i)
        #pragma unroll
        for (int j = 0; j < 4; ++j)
            acc[i][j] = (floatx4){0.f, 0.f, 0.f, 0.f};

    for (int k0 = 0; k0 < K; k0 += TKK) {
        // ---- A (f32): 16 chunks of 8 rows, 2 per wave ----
        #pragma unroll
        for (int cc = 0; cc < 2; ++cc) {
            const int c = wave * 2 + cc;
            __builtin_amdgcn_global_load_lds(
                (glob_float*)(A + (long long)(m0 + c * 8 + ar8) * K + k0 + au),
                (lds_float*)(Asf + c * 256), 16, 0, 0);
        }
        // ---- B (bf16): 8 chunks of 16 rows, 1 per wave ----
        __builtin_amdgcn_global_load_lds(
            (glob_short*)(B + (long long)(n0 + wave * 16 + sr) * K + k0 + sc),
            (lds_short*)(Bs + wave * 512), 16, 0, 0);
        __syncthreads();
        bf16x8 af[2], bfr[4];
        #pragma unroll
        for (int i = 0; i < 2; ++i) {
            const int R = wm + i * 16 + (lane & 15);
            const float4 u0 = *(const float4*)&Asf[R * TKK + (((h * 2)     ^ (R & 7)) * 4)];
            const float4 u1 = *(const float4*)&Asf[R * TKK + (((h * 2 + 1) ^ (R & 7)) * 4)];
            af[i][0] = f2bf(u0.x); af[i][1] = f2bf(u0.y);
            af[i][2] = f2bf(u0.z); af[i][3] = f2bf(u0.w);
            af[i][4] = f2bf(u1.x); af[i][5] = f2bf(u1.y);
            af[i][6] = f2bf(u1.z); af[i][7] = f2bf(u1.w);
        }
        #pragma unroll
        for (int j = 0; j < 4; ++j)
            bfr[j] = *(const bf16x8*)&Bs[(wn + j * 16 + (lane & 15)) * TKK + fc];
        #pragma unroll
        for (int i = 0; i < 2; ++i)
            #pragma unroll
            for (int j = 0; j < 4; ++j)
                acc[i][j] = __builtin_amdgcn_mfma_f32_16x16x32_bf16(af[i], bfr[j], acc[i][j], 0, 0, 0);
        __syncthreads();
    }

    // Epilogue: C/D layout col=lane&15, row=(lane>>4)*4+reg (m89-verified)
    #pragma unroll
    for (int i = 0; i < 2; ++i) {
        const int rbase = m0 + wm + i * 16 + (lane >> 4) * 4;
        #pragma unroll
        for (int j = 0; j < 4; ++j) {
            const int col = n0 + wn + j * 16 + (lane & 15);
            const float bb = bias[col];
            #pragma unroll
            for (int r = 0; r < 4; ++r)
                C[(long long)(rbase + r) * N + col] = f2bf((acc[i][j][r] + bb) * esc);
        }
    }
}

// ---- PV gemm: out = E @ vpT^T ---- (R9 structure, unchanged)
__global__ __launch_bounds__(512) void pv_gemm(
    const short* __restrict__ Eg, const short* __restrict__ vpTg,
    float* __restrict__ outg, int N, int K,
    long long sA, long long sB, long long sC)
{
    __shared__ short As[2][128 * TKK];
    __shared__ short Bs[2][64 * TKK];
    const int bz = blockIdx.z;
    const short* A = Eg   + (long long)bz * sA;
    const short* B = vpTg + (long long)bz * sB;
    float*       C = outg + (long long)bz * sC;

    const int m0 = blockIdx.x * 128;
    const int n0 = blockIdx.y * 64;
    const int t    = threadIdx.x;
    const int wave = t >> 6;
    const int lane = t & 63;
    const int wm = (wave >> 1) * 32;
    const int wn = (wave & 1)  * 32;
    const int sr = lane >> 2;
    const int sc = STAGE_SC(lane);
    const int fc = FRAG_FC(lane);

    floatx4 acc[2][2];
    #pragma unroll
    for (int i = 0; i < 2; ++i)
        #pragma unroll
        for (int j = 0; j < 2; ++j)
            acc[i][j] = (floatx4){0.f, 0.f, 0.f, 0.f};

    for (int k0 = 0; k0 < K; k0 += 2 * TKK) {
        #pragma unroll
        for (int h = 0; h < 2; ++h) {
            const int kk = k0 + h * TKK;
            __builtin_amdgcn_global_load_lds(
                (glob_short*)(A + (long long)(m0 + wave * 16 + sr) * K + kk + sc),
                (lds_short*)(As[h] + wave * 512), 16, 0, 0);
            if (wave < 4)
                __builtin_amdgcn_global_load_lds(
                    (glob_short*)(B + (long long)(n0 + wave * 16 + sr) * K + kk + sc),
                    (lds_short*)(Bs[h] + wave * 512), 16, 0, 0);
        }
        __syncthreads();
        #pragma unroll
        for (int h = 0; h < 2; ++h) {
            bf16x8 af[2], bfr[2];
            #pragma unroll
            for (int i = 0; i < 2; ++i)
                af[i] = *(const bf16x8*)&As[h][(wm + i * 16 + (lane & 15)) * TKK + fc];
            #pragma unroll
            for (int j = 0; j < 2; ++j)
                bfr[j] = *(const bf16x8*)&Bs[h][(wn + j * 16 + (lane & 15)) * TKK + fc];
            #pragma unroll
            for (int i = 0; i < 2; ++i)
                #pragma unroll
                for (int j = 0; j < 2; ++j)
                    acc[i][j] = __builtin_amdgcn_mfma_f32_16x16x32_bf16(af[i], bfr[j], acc[i][j], 0, 0, 0);
        }
        __syncthreads();
    }

    #pragma unroll
    for (int i = 0; i < 2; ++i) {
        const int rbase = m0 + wm + i * 16 + (lane >> 4) * 4;
        #pragma unroll
        for (int j = 0; j < 2; ++j) {
            const int col = n0 + wn + j * 16 + (lane & 15);
            #pragma unroll
            for (int r = 0; r < 4; ++r)
                C[(long long)(rbase + r) * N + col] = acc[i][j][r];
        }
    }
}

// ---- NT MFMA gemm with fused exp2 + column-sum (R10 structure, unchanged) ----
__global__ __launch_bounds__(512) void gemm_nt_exp_colsum(
    const short* __restrict__ A, const short* __restrict__ B,
    short* __restrict__ E, float* __restrict__ colsum,
    int N, int K, long long sA, long long sB, long long sE)
{
    __shared__ short As[2][128 * TKK];
    __shared__ short Bs[2][128 * TKK];
    __shared__ float wsum[8][64];
    const int bz = blockIdx.z;
    A += (long long)bz * sA;
    B += (long long)bz * sB;
    E += (long long)bz * sE;
    colsum += (long long)bz * N;

    const int m0 = blockIdx.x * 128;
    const int n0 = blockIdx.y * 128;
    const int t    = threadIdx.x;
    const int wave = t >> 6;
    const int lane = t & 63;
    const int wm = (wave >> 1) * 32;
    const int wn = (wave & 1)  * 64;
    const int sr = lane >> 2;
    const int sc = STAGE_SC(lane);
    const int fc = FRAG_FC(lane);

    floatx4 acc[2][4];
    #pragma unroll
    for (int i = 0; i < 2; ++i)
        #pragma unroll
        for (int j = 0; j < 4; ++j)
            acc[i][j] = (floatx4){0.f, 0.f, 0.f, 0.f};

    for (int k0 = 0; k0 < K; k0 += 2 * TKK) {
        #pragma unroll
        for (int h = 0; h < 2; ++h) {
            const int kk = k0 + h * TKK;
            const int r = wave * 16 + sr;
            __builtin_amdgcn_global_load_lds(
                (glob_short*)(A + (long long)(m0 + r) * K + kk + sc),
                (lds_short*)(As[h] + wave * 512), 16, 0, 0);
            __builtin_amdgcn_global_load_lds(
                (glob_short*)(B + (long long)(n0 + r) * K + kk + sc),
                (lds_short*)(Bs[h] + wave * 512), 16, 0, 0);
        }
        __syncthreads();
        #pragma unroll
        for (int h = 0; h < 2; ++h) {
            bf16x8 af[2], bfr[4];
            #pragma unroll
            for (int i = 0; i < 2; ++i)
                af[i] = *(const bf16x8*)&As[h][(wm + i * 16 + (lane & 15)) * TKK + fc];
            #pragma unroll
            for (int j = 0; j < 4; ++j)
                bfr[j] = *(const bf16x8*)&Bs[h][(wn + j * 16 + (lane & 15)) * TKK + fc];
            #pragma unroll
            for (int i = 0; i < 2; ++i)
                #pragma unroll
                for (int j = 0; j < 4; ++j)
                    acc[i][j] = __builtin_amdgcn_mfma_f32_16x16x32_bf16(af[i], bfr[j], acc[i][j], 0, 0, 0);
        }
        __syncthreads();
    }

    float csum[4] = {0.f, 0.f, 0.f, 0.f};
    #pragma unroll
    for (int i = 0; i < 2; ++i) {
        const int rbase = wm + i * 16 + (lane >> 4) * 4;
        #pragma unroll
        for (int j = 0; j < 4; ++j) {
            const int col = wn + j * 16 + (lane & 15);
            #pragma unroll
            for (int r = 0; r < 4; ++r) {
                const float e = exp2_fast(acc[i][j][r]);
                E[(long long)(m0 + rbase + r) * N + (n0 + col)] = f2bf(e);
                csum[j] += e;
            }
        }
    }
    #pragma unroll
    for (int j = 0; j < 4; ++j) {
        csum[j] += __shfl_xor(csum[j], 16);
        csum[j] += __shfl_xor(csum[j], 32);
    }
    if (lane < 16) {
        #pragma unroll
        for (int j = 0; j < 4; ++j)
            wsum[wave][j * 16 + lane] = csum[j];
    }
    __syncthreads();
    if (t < 128) {
        const int half = t >> 6;
        const int col  = t & 63;
        const float s = wsum[half][col] + wsum[half + 2][col]
                      + wsum[half + 4][col] + wsum[half + 6][col];
        atomicAdd(&colsum[n0 + half * 64 + col], s);
    }
}

// ---- bf16 transpose + per-row scale: out[c][r] = in[r][c] / colsum[r] ----
__global__ __launch_bounds__(256) void transpose_scale_bf16(
    const short* __restrict__ in, const float* __restrict__ colsum,
    short* __restrict__ out, int R, int Cc)
{
    __shared__ short tile[32][33];
    const int b = blockIdx.z;
    in  += (long long)b * R * Cc;
    out += (long long)b * R * Cc;
    colsum += (long long)b * R;
    const int c0 = blockIdx.x * 32, r0 = blockIdx.y * 32;
    const int tx = threadIdx.x & 31, ty = threadIdx.x >> 5;
    #pragma unroll
    for (int rr = ty; rr < 32; rr += 8) {
        const float rs = 1.f / colsum[r0 + rr];
        tile[rr][tx] = f2bf(bf2f(in[(long long)(r0 + rr) * Cc + c0 + tx]) * rs);
    }
    __syncthreads();
    #pragma unroll
    for (int rr = ty; rr < 32; rr += 8)
        out[(long long)(c0 + rr) * R + r0 + tx] = tile[tx][rr];
}

extern "C" void kernel_launch(void* const* d_in, const int* in_sizes, int n_in,
                              void* d_out, int out_size, void* d_ws, size_t ws_size,
                              hipStream_t stream) {
    const float* q  = (const float*)d_in[0];
    const float* k  = (const float*)d_in[1];
    const float* v  = (const float*)d_in[2];
    const float* Wq = (const float*)d_in[3];
    const float* bq = (const float*)d_in[4];
    const float* Wk = (const float*)d_in[5];
    const float* bk = (const float*)d_in[6];
    const float* Wv = (const float*)d_in[7];
    const float* bv = (const float*)d_in[8];
    float* out = (float*)d_out;

    const int Bb = 8, L = 2048, D = 512;
    const long long BLD = (long long)Bb * L * D;   // 8,388,608
    const long long BLL = (long long)Bb * L * L;   // 33,554,432
    const long long DD  = (long long)D * D;

    // ---- workspace layout (shorts unless noted) ----
    short* base  = (short*)d_ws;
    short* qp_bf = base;                 // BLD
    short* kp_bf = qp_bf + BLD;         // BLD
    short* vp_bf = kp_bf + BLD;         // BLD
    short* vpT   = vp_bf + BLD;         // BLD
    short* Wq_bf = vpT   + BLD;         // DD
    short* Wk_bf = Wq_bf + DD;          // DD
    short* Wv_bf = Wk_bf + DD;          // DD
    short* E_bf  = Wv_bf + DD;          // BLL shorts
    float* colsum = (float*)(E_bf + BLL); // B*L floats

    dim3 blk(256);

    // 1) W casts + colsum zero (448 blocks)
    prep<<<dim3(448), blk, 0, stream>>>(Wq, Wk, Wv, Wq_bf, Wk_bf, Wv_bf, colsum);

    // 2) fused projections from f32 inputs: M=B*L, N=D, K=D, 512 thr
    dim3 gproj((Bb * L) / 128, D / 128, 3);
    proj_gemm<<<gproj, dim3(512), 0, stream>>>(q, k, v,
                                               Wq_bf, Wk_bf, Wv_bf,
                                               bq, bk, bv,
                                               qp_bf, kp_bf, vp_bf, D, D);

    // 3) E = exp2(qp @ kp^T), colsum[b,j] = sum_i E[b,i,j], 512 thr
    dim3 gS(L / 128, L / 128, Bb);
    gemm_nt_exp_colsum<<<gS, dim3(512), 0, stream>>>(qp_bf, kp_bf, E_bf, colsum,
                                                     L, D,
                                                     (long long)L * D, (long long)L * D,
                                                     (long long)L * L);

    // 4) vpT[d][j] = vp[j][d] / colsum[j]  per batch
    dim3 gT(D / 32, L / 32, Bb);
    transpose_scale_bf16<<<gT, blk, 0, stream>>>(vp_bf, colsum, vpT, L, D);

    // 5) out = E @ vpT^T : M=L (128-tiles), N=D (64-tiles), K=L, 512 thr
    dim3 gO(L / 128, D / 64, Bb);
    pv_gemm<<<gO, dim3(512), 0, stream>>>(E_bf, vpT, out, D, L,
                                          (long long)L * L, (long long)D * L,
                                          (long long)L * D);
}